// Round 13
// baseline (773.525 us; speedup 1.0000x reference)
//
#include <hip/hip_runtime.h>
#include <hip/hip_bf16.h>
#include <math.h>

// NeuralCDE fused kernel, round 13 = round 12 + three latency cuts.
// 256 blocks x 256 threads (4 waves); block owns 16 batch rows for all 256
// RK4 steps; wave w owns output channels [32w,32w+32). Operand-swapped MFMA
// (W^T = A in regs, X^T = B from LDS) with the diagonal register identity
// (k = 32*slice + 16(i>>2) + 4q + (i&3)): a wave's D-frag after act+cvt_pk IS
// its own-slice B-operand -> own-slice MFMAs + bias-init issue PRE-barrier,
// 3 ds_read_b128 post-barrier, exchange write is one ds_write_b128. Weights
// rotation-ordered (wave w keeps slice (w+j)&3 at index j): all hot-loop
// indices are compile-time literals. All sync is real __syncthreads().
// vs round 12 (693us):
//  - P/Q depth-2 MFMA chains (post-barrier dep: 2 MFMA + 1 add, was 3 MFMA)
//  - coeff prefetch issued inside stage-1 L1's post-barrier region (cuts the
//    once-per-piece vmcnt-drain stall at the next __syncthreads)
//  - stage epilogues emit h before sacc/zr updates (shorter A->ds_write path)

typedef short bf16x8 __attribute__((ext_vector_type(8)));
typedef float f32x4  __attribute__((ext_vector_type(4)));
typedef unsigned int u32x4 __attribute__((ext_vector_type(4)));

__device__ __forceinline__ f32x4 MFMA16(bf16x8 a, bf16x8 b, f32x4 c) {
  return __builtin_amdgcn_mfma_f32_16x16x32_bf16(a, b, c, 0, 0, 0);
}

__device__ __forceinline__ unsigned short f2bf(float x) {  // weight prep only
  unsigned int u = __float_as_uint(x);
  u += 0x7FFFu + ((u >> 16) & 1u);
  return (unsigned short)(u >> 16);
}

__device__ __forceinline__ unsigned int cvt_pk(float lo, float hi) {
  unsigned int r;  // D[15:0]=bf16(lo), D[31:16]=bf16(hi), RNE
  asm("v_cvt_pk_bf16_f32 %0, %1, %2" : "=v"(r) : "v"(lo), "v"(hi));
  return r;
}

__global__ __launch_bounds__(256, 1) void cde_fused(
    const float* __restrict__ z0, const float* __restrict__ coeffs,
    const float* __restrict__ W1, const float* __restrict__ b1,
    const float* __restrict__ W2, const float* __restrict__ b2,
    const float* __restrict__ W3, const float* __restrict__ b3,
    const float* __restrict__ Wr, const float* __restrict__ br,
    float* __restrict__ out) {
  // [2][16 rows][136 shorts]; row stride 272 B; slice s at byte-offset 64s.
  __shared__ __align__(16) unsigned short zbuf[2][16][136];
  char* const lds = (char*)zbuf;

  const int tid  = (int)threadIdx.x;
  const int lane = tid & 63;
  const int wv   = tid >> 6;        // wave 0..3 (owns k-slice wv)
  const int l15  = lane & 15;       // batch row within tile
  const int q    = lane >> 4;       // 0..3
  const int row0 = (int)blockIdx.x * 16;

  const f32x4 ZERO4 = {0.f, 0.f, 0.f, 0.f};

  // exchange addresses: slice s lives at byte l15*272 + 64s + 16q
  const int exb  = l15 * 272 + 16 * q;
  const int ownb = exb + 64 * wv;                       // our b128 write
  const int off1 = exb + 64 * ((wv + 1) & 3);           // read, rotation j=1
  const int off2 = exb + 64 * ((wv + 2) & 3);           // j=2
  const int off3 = exb + 64 * ((wv + 3) & 3);           // j=3

  // ------------- weight A-frags, rotation-ordered, B-identity K-dim ---------
  // index [mt][j] holds slice s=(wv+j)&3: elem i = W[32s+16(i>>2)+4q+(i&3)][col]
  bf16x8 wf1[2][4], wf2[2][4], wf3[2][4];
#pragma unroll
  for (int mt = 0; mt < 2; ++mt) {
    const int col = 32 * wv + 16 * mt + l15;
#pragma unroll
    for (int js = 0; js < 4; ++js) {
      const int s = (wv + js) & 3;
      bf16x8 fa, fb, fc;
#pragma unroll
      for (int i = 0; i < 8; ++i) {
        const int k = 32 * s + 16 * (i >> 2) + 4 * q + (i & 3);
        fa[i] = (short)f2bf(W1[k * 128 + col]);
        fb[i] = (short)f2bf(W2[k * 128 + col]);
        fc[i] = (short)f2bf(W3[k * 128 + col]);
      }
      wf1[mt][js] = fa; wf2[mt][js] = fb; wf3[mt][js] = fc;
    }
  }
  // biases (accumulator init): D elem r of tile mt = ch 32wv+16mt+4q+r
  f32x4 bv1[2], bv2[2], bv3[2];
#pragma unroll
  for (int mt = 0; mt < 2; ++mt) {
    bv1[mt] = *(const f32x4*)(b1 + 32 * wv + 16 * mt + 4 * q);
    bv2[mt] = *(const f32x4*)(b2 + 32 * wv + 16 * mt + 4 * q);
    bv3[mt] = *(const f32x4*)(b3 + 32 * wv + 16 * mt + 4 * q);
  }

  // ------------- coeff registers (e = mt*4+r -> row l15, ch 32wv+16mt+4q+r) --
  f32x4 cf[8];
  auto coeff_load = [&](int p) {
    const float* cb = coeffs + ((size_t)(row0 + l15) * 64 + p) * 512;
#pragma unroll
    for (int mt = 0; mt < 2; ++mt)
#pragma unroll
      for (int r = 0; r < 4; ++r)
        cf[mt * 4 + r] = *(const f32x4*)(cb + (32 * wv + 16 * mt + 4 * q + r) * 4);
  };
  float c1v[8], c2b[8], c3b[8];  // c1, 2*c2, 3*c3
  auto coeff_adopt = [&]() {
#pragma unroll
    for (int e = 0; e < 8; ++e) {
      c1v[e] = cf[e][1]; c2b[e] = 2.f * cf[e][2]; c3b[e] = 3.f * cf[e][3];
    }
  };

  // own B-frag registers (packed words, doubles as the LDS exchange payload)
  u32x4 zb;
  auto emit = [&](const float(&h)[8], int wbuf) {  // pack + keep + write b128
    u32x4 t;
    t[0] = cvt_pk(h[0], h[1]); t[1] = cvt_pk(h[2], h[3]);
    t[2] = cvt_pk(h[4], h[5]); t[3] = cvt_pk(h[6], h[7]);
    zb = t;
    *(u32x4*)(lds + wbuf * 4352 + ownb) = t;
  };

  // ------------- prologue -------------
  float zr[8];
  {
    const float* zp = z0 + (size_t)(row0 + l15) * 128 + 32 * wv + 4 * q;
    const f32x4 za = *(const f32x4*)zp;
    const f32x4 zc = *(const f32x4*)(zp + 16);
#pragma unroll
    for (int r = 0; r < 4; ++r) { zr[r] = za[r]; zr[4 + r] = zc[r]; }
  }
  coeff_load(0);
  coeff_adopt();
  {
    float h[8];
#pragma unroll
    for (int e = 0; e < 8; ++e) h[e] = zr[e];
    emit(h, 0);
  }

  float kx[8], sacc[8], dxb[8], dxm[8];
#pragma unroll
  for (int e = 0; e < 8; ++e) dxm[e] = c1v[e];  // dX at t=0 (s=0, piece 0)

  // one layer: 2 own-slice MFMAs pre-barrier (from zb regs), then 3 reads;
  // P/Q depth-2 chains post-barrier (P: own+j1, Q: j2+j3), one add per tile.
  // clp >= 0: issue coeff prefetch for piece clp right after the ds_reads
  // (max distance to the next vmcnt-draining __syncthreads).
  auto layer = [&](const bf16x8(&wf)[2][4], const f32x4(&bv)[2], int rb,
                   int clp, f32x4& A0, f32x4& A1) {
    const bf16x8 xo = __builtin_bit_cast(bf16x8, zb);
    f32x4 P0 = MFMA16(wf[0][0], xo, bv[0]);
    f32x4 P1 = MFMA16(wf[1][0], xo, bv[1]);
    __syncthreads();
    const char* base = lds + rb * 4352;
    const bf16x8 x1 = *(const bf16x8*)(base + off1);
    const bf16x8 x2 = *(const bf16x8*)(base + off2);
    const bf16x8 x3 = *(const bf16x8*)(base + off3);
    if (clp >= 0) coeff_load(clp);
    f32x4 Q0 = MFMA16(wf[0][2], x2, ZERO4);
    f32x4 Q1 = MFMA16(wf[1][2], x2, ZERO4);
    P0 = MFMA16(wf[0][1], x1, P0);
    P1 = MFMA16(wf[1][1], x1, P1);
    Q0 = MFMA16(wf[0][3], x3, Q0);
    Q1 = MFMA16(wf[1][3], x3, Q1);
    A0 = P0 + Q0; A1 = P1 + Q1;
  };

  // one MLP eval; exchange buffers: L1 rd sp wr sp^1, L2 rd sp^1 wr sp,
  // L3 rd sp; result (incl. b3) -> kx. clp forwarded to L1 only.
  auto run_f = [&](int sp, int clp) {
    f32x4 A0, A1;
    float h[8];
    layer(wf1, bv1, sp, clp, A0, A1);
#pragma unroll
    for (int r = 0; r < 4; ++r) {  // ELU(v) = max(v, exp(min(v,0))-1)
      h[r]     = fmaxf(A0[r], __expf(fminf(A0[r], 0.f)) - 1.f);
      h[4 + r] = fmaxf(A1[r], __expf(fminf(A1[r], 0.f)) - 1.f);
    }
    emit(h, sp ^ 1);
    layer(wf2, bv2, sp ^ 1, -1, A0, A1);
#pragma unroll
    for (int r = 0; r < 4; ++r) {
      h[r] = fmaxf(A0[r], 0.f); h[4 + r] = fmaxf(A1[r], 0.f);  // ReLU
    }
    emit(h, sp);
    layer(wf3, bv3, sp, -1, A0, A1);
#pragma unroll
    for (int r = 0; r < 4; ++r) { kx[r] = A0[r]; kx[4 + r] = A1[r]; }
  };

  // ------------- main loop: 64 pieces x 4 unrolled substeps -------------
#pragma unroll 1
  for (int p = 0; p < 64; ++p) {
    const bool pre = p < 63;

#pragma unroll
    for (int sub = 0; sub < 4; ++sub) {
      const float s0 = 0.25f * (float)sub;  // compile-time

      // ---- stage 1: k1 = f(z)*dX(s0); dx carried in dxm; coeff prefetch ----
      run_f(0, (sub == 0 && pre) ? (p + 1) : -1);
      {
        float h[8];
#pragma unroll
        for (int e = 0; e < 8; ++e) {   // emit-first: h on the critical path
          kx[e] *= dxm[e];
          h[e] = fmaf(0.125f, kx[e], zr[e]);
        }
        emit(h, 1);
#pragma unroll
        for (int e = 0; e < 8; ++e) sacc[e] = kx[e];
      }

      // ---- stage 2: k2 at s0+0.125 ----
      run_f(1, -1);
      {
        const float sb = s0 + 0.125f;
        float h[8];
#pragma unroll
        for (int e = 0; e < 8; ++e) {
          dxb[e] = c1v[e] + (c2b[e] + c3b[e] * sb) * sb;
          kx[e] *= dxb[e];
          h[e] = fmaf(0.125f, kx[e], zr[e]);
        }
        emit(h, 0);
#pragma unroll
        for (int e = 0; e < 8; ++e) sacc[e] += 2.f * kx[e];
      }

      // ---- stage 3: k3 at same s as k2 (dx reused) ----
      run_f(0, -1);
      {
        float h[8];
#pragma unroll
        for (int e = 0; e < 8; ++e) {
          kx[e] *= dxb[e];
          h[e] = fmaf(0.25f, kx[e], zr[e]);
        }
        emit(h, 1);
#pragma unroll
        for (int e = 0; e < 8; ++e) sacc[e] += 2.f * kx[e];
      }

      // ---- stage 4: k4 at t+dt; dxm set for NEXT stage 1 too ----
      run_f(1, -1);
      if (sub == 3) {
        if (pre) {
#pragma unroll
          for (int e = 0; e < 8; ++e) dxm[e] = cf[e][1];  // next piece, s=0
        } else {
#pragma unroll
          for (int e = 0; e < 8; ++e) dxm[e] = c1v[e] + c2b[e] + c3b[e];  // s=1
        }
      } else {
        const float sc = s0 + 0.25f;
#pragma unroll
        for (int e = 0; e < 8; ++e)
          dxm[e] = c1v[e] + (c2b[e] + c3b[e] * sc) * sc;
      }
      {
        float h[8];
#pragma unroll
        for (int e = 0; e < 8; ++e) {
          const float k4 = kx[e] * dxm[e];
          sacc[e] += k4;
          zr[e] = fmaf(0.25f / 6.f, sacc[e], zr[e]);
          h[e] = zr[e];
        }
        emit(h, 0);  // next step's f-input -> buf0
      }
    }
    if (pre) coeff_adopt();
  }

  // ------------- readout: out = zT @ Wr + br -------------
  __syncthreads();  // all exchange reads done; reuse LDS as fp32 zf[16][132]
  {
    float* zf = (float*)lds;
    *(f32x4*)(zf + l15 * 132 + 32 * wv + 4 * q)      = f32x4{zr[0], zr[1], zr[2], zr[3]};
    *(f32x4*)(zf + l15 * 132 + 32 * wv + 16 + 4 * q) = f32x4{zr[4], zr[5], zr[6], zr[7]};
  }
  __syncthreads();
  if (tid < 160) {
    const int row = tid / 10, o = tid - row * 10;
    const float* zf = (const float*)lds;
    float acc = br[o];
#pragma unroll 4
    for (int ch = 0; ch < 128; ++ch)
      acc = fmaf(zf[row * 132 + ch], Wr[ch * 10 + o], acc);
    out[(size_t)(row0 + row) * 10 + o] = acc;
  }
}

extern "C" void kernel_launch(void* const* d_in, const int* in_sizes, int n_in,
                              void* d_out, int out_size, void* d_ws, size_t ws_size,
                              hipStream_t stream) {
  const float* z0     = (const float*)d_in[0];
  const float* coeffs = (const float*)d_in[1];
  const float* W1 = (const float*)d_in[2]; const float* b1 = (const float*)d_in[3];
  const float* W2 = (const float*)d_in[4]; const float* b2 = (const float*)d_in[5];
  const float* W3 = (const float*)d_in[6]; const float* b3 = (const float*)d_in[7];
  const float* Wr = (const float*)d_in[8]; const float* br = (const float*)d_in[9];
  hipLaunchKernelGGL(cde_fused, dim3(256), dim3(256), 0, stream,
                     z0, coeffs, W1, b1, W2, b2, W3, b3, Wr, br, (float*)d_out);
}

// Round 14
// 731.248 us; speedup vs baseline: 1.0578x; 1.0578x over previous
//
#include <hip/hip_runtime.h>
#include <hip/hip_bf16.h>
#include <math.h>

// NeuralCDE fused kernel, round 14 = round 12 (693us champion) + vectorized
// epilogue math (f32x4-typed state -> packed fp32 VALU: v_pk_fma_f32 etc).
// 256 blocks x 256 threads (4 waves); block owns 16 batch rows for all 256
// RK4 steps; wave w owns output channels [32w,32w+32). Operand-swapped MFMA
// (W^T = A in regs, X^T = B from LDS) with the diagonal register identity
// (k = 32*slice + 16(i>>2) + 4q + (i&3)): a wave's D-frag after act+cvt_pk IS
// its own-slice B-operand -> own-slice MFMAs + bias-init issue PRE-barrier,
// 3 ds_read_b128 post-barrier, exchange write is one ds_write_b128. Weights
// rotation-ordered (wave w keeps slice (w+j)&3 at index j): all hot-loop
// indices compile-time literals. Single depth-4 MFMA chains (P/Q split is a
// proven regression: r8 +110us, r13 +80us). All sync = real __syncthreads()
// (r11's asm barrier raced: ds_reads can hoist past the IntrNoMem s_barrier
// intrinsic). Coeff prefetch at piece-loop top (r12 placement). dxm carry:
// stage-4's dX(t+dt) is reused as next stage-1's dX(t).

typedef short bf16x8 __attribute__((ext_vector_type(8)));
typedef float f32x4  __attribute__((ext_vector_type(4)));
typedef unsigned int u32x4 __attribute__((ext_vector_type(4)));

__device__ __forceinline__ f32x4 MFMA16(bf16x8 a, bf16x8 b, f32x4 c) {
  return __builtin_amdgcn_mfma_f32_16x16x32_bf16(a, b, c, 0, 0, 0);
}

__device__ __forceinline__ unsigned short f2bf(float x) {  // weight prep only
  unsigned int u = __float_as_uint(x);
  u += 0x7FFFu + ((u >> 16) & 1u);
  return (unsigned short)(u >> 16);
}

__device__ __forceinline__ unsigned int cvt_pk(float lo, float hi) {
  unsigned int r;  // D[15:0]=bf16(lo), D[31:16]=bf16(hi), RNE
  asm("v_cvt_pk_bf16_f32 %0, %1, %2" : "=v"(r) : "v"(lo), "v"(hi));
  return r;
}

__device__ __forceinline__ f32x4 elu4(f32x4 v) {
  const f32x4 z4 = {0.f, 0.f, 0.f, 0.f};
  f32x4 neg = __builtin_elementwise_min(v, z4);
  f32x4 e;
  e[0] = __expf(neg[0]); e[1] = __expf(neg[1]);
  e[2] = __expf(neg[2]); e[3] = __expf(neg[3]);
  return __builtin_elementwise_max(v, e - 1.0f);
}

__device__ __forceinline__ f32x4 relu4(f32x4 v) {
  const f32x4 z4 = {0.f, 0.f, 0.f, 0.f};
  return __builtin_elementwise_max(v, z4);
}

__global__ __launch_bounds__(256, 1) void cde_fused(
    const float* __restrict__ z0, const float* __restrict__ coeffs,
    const float* __restrict__ W1, const float* __restrict__ b1,
    const float* __restrict__ W2, const float* __restrict__ b2,
    const float* __restrict__ W3, const float* __restrict__ b3,
    const float* __restrict__ Wr, const float* __restrict__ br,
    float* __restrict__ out) {
  // [2][16 rows][136 shorts]; row stride 272 B; slice s at byte-offset 64s.
  __shared__ __align__(16) unsigned short zbuf[2][16][136];
  char* const lds = (char*)zbuf;

  const int tid  = (int)threadIdx.x;
  const int lane = tid & 63;
  const int wv   = tid >> 6;        // wave 0..3 (owns k-slice wv)
  const int l15  = lane & 15;       // batch row within tile
  const int q    = lane >> 4;       // 0..3
  const int row0 = (int)blockIdx.x * 16;

  // exchange addresses: slice s lives at byte l15*272 + 64s + 16q
  const int exb  = l15 * 272 + 16 * q;
  const int ownb = exb + 64 * wv;                       // our b128 write
  const int off1 = exb + 64 * ((wv + 1) & 3);           // read, rotation j=1
  const int off2 = exb + 64 * ((wv + 2) & 3);           // j=2
  const int off3 = exb + 64 * ((wv + 3) & 3);           // j=3

  // ------------- weight A-frags, rotation-ordered, B-identity K-dim ---------
  // index [mt][j] holds slice s=(wv+j)&3: elem i = W[32s+16(i>>2)+4q+(i&3)][col]
  bf16x8 wf1[2][4], wf2[2][4], wf3[2][4];
#pragma unroll
  for (int mt = 0; mt < 2; ++mt) {
    const int col = 32 * wv + 16 * mt + l15;
#pragma unroll
    for (int js = 0; js < 4; ++js) {
      const int s = (wv + js) & 3;
      bf16x8 fa, fb, fc;
#pragma unroll
      for (int i = 0; i < 8; ++i) {
        const int k = 32 * s + 16 * (i >> 2) + 4 * q + (i & 3);
        fa[i] = (short)f2bf(W1[k * 128 + col]);
        fb[i] = (short)f2bf(W2[k * 128 + col]);
        fc[i] = (short)f2bf(W3[k * 128 + col]);
      }
      wf1[mt][js] = fa; wf2[mt][js] = fb; wf3[mt][js] = fc;
    }
  }
  // biases (accumulator init): D elem r of tile mt = ch 32wv+16mt+4q+r
  f32x4 bv1[2], bv2[2], bv3[2];
#pragma unroll
  for (int mt = 0; mt < 2; ++mt) {
    bv1[mt] = *(const f32x4*)(b1 + 32 * wv + 16 * mt + 4 * q);
    bv2[mt] = *(const f32x4*)(b2 + 32 * wv + 16 * mt + 4 * q);
    bv3[mt] = *(const f32x4*)(b3 + 32 * wv + 16 * mt + 4 * q);
  }

  // ------------- coeff registers (e = mt*4+r -> row l15, ch 32wv+16mt+4q+r) --
  f32x4 cf[8];
  auto coeff_load = [&](int p) {
    const float* cb = coeffs + ((size_t)(row0 + l15) * 64 + p) * 512;
#pragma unroll
    for (int mt = 0; mt < 2; ++mt)
#pragma unroll
      for (int r = 0; r < 4; ++r)
        cf[mt * 4 + r] = *(const f32x4*)(cb + (32 * wv + 16 * mt + 4 * q + r) * 4);
  };
  // per-piece coefficient VECTORS: element r of A/B = channel elem (mt 0/1)
  f32x4 c1A, c1B, c2A, c2B, c3A, c3B;  // c1, 2*c2, 3*c3
  auto coeff_adopt = [&]() {
#pragma unroll
    for (int r = 0; r < 4; ++r) {
      c1A[r] = cf[r][1];     c1B[r] = cf[4 + r][1];
      c2A[r] = 2.f * cf[r][2]; c2B[r] = 2.f * cf[4 + r][2];
      c3A[r] = 3.f * cf[r][3]; c3B[r] = 3.f * cf[4 + r][3];
    }
  };

  // own B-frag registers (packed words, doubles as the LDS exchange payload)
  u32x4 zb;
  auto emit = [&](f32x4 ha, f32x4 hb, int wbuf) {  // pack + keep + write b128
    u32x4 t;
    t[0] = cvt_pk(ha[0], ha[1]); t[1] = cvt_pk(ha[2], ha[3]);
    t[2] = cvt_pk(hb[0], hb[1]); t[3] = cvt_pk(hb[2], hb[3]);
    zb = t;
    *(u32x4*)(lds + wbuf * 4352 + ownb) = t;
  };

  // ------------- prologue -------------
  f32x4 zrA, zrB;
  {
    const float* zp = z0 + (size_t)(row0 + l15) * 128 + 32 * wv + 4 * q;
    zrA = *(const f32x4*)zp;
    zrB = *(const f32x4*)(zp + 16);
  }
  coeff_load(0);
  coeff_adopt();
  emit(zrA, zrB, 0);

  f32x4 kxA, kxB, saccA, saccB, dxbA, dxbB, dxmA, dxmB;
  dxmA = c1A; dxmB = c1B;  // dX at t=0 (s=0, piece 0)

  // one layer: 2 own-slice MFMAs pre-barrier (from zb regs), then 3 reads +
  // 6 MFMAs; single depth-4 chain per tile; ALL array indices literal.
  auto layer = [&](const bf16x8(&wf)[2][4], const f32x4(&bv)[2], int rb,
                   f32x4& A0, f32x4& A1) {
    const bf16x8 xo = __builtin_bit_cast(bf16x8, zb);
    f32x4 a0 = MFMA16(wf[0][0], xo, bv[0]);
    f32x4 a1 = MFMA16(wf[1][0], xo, bv[1]);
    __syncthreads();
    const char* base = lds + rb * 4352;
    const bf16x8 x1 = *(const bf16x8*)(base + off1);
    const bf16x8 x2 = *(const bf16x8*)(base + off2);
    const bf16x8 x3 = *(const bf16x8*)(base + off3);
    a0 = MFMA16(wf[0][1], x1, a0);
    a1 = MFMA16(wf[1][1], x1, a1);
    a0 = MFMA16(wf[0][2], x2, a0);
    a1 = MFMA16(wf[1][2], x2, a1);
    a0 = MFMA16(wf[0][3], x3, a0);
    a1 = MFMA16(wf[1][3], x3, a1);
    A0 = a0; A1 = a1;
  };

  // one MLP eval; exchange buffers: L1 rd sp wr sp^1, L2 rd sp^1 wr sp,
  // L3 rd sp; result (incl. b3) -> kxA/kxB
  auto run_f = [&](int sp) {
    f32x4 A0, A1;
    layer(wf1, bv1, sp, A0, A1);
    emit(elu4(A0), elu4(A1), sp ^ 1);      // ELU
    layer(wf2, bv2, sp ^ 1, A0, A1);
    emit(relu4(A0), relu4(A1), sp);        // ReLU
    layer(wf3, bv3, sp, A0, A1);
    kxA = A0; kxB = A1;
  };

  // ------------- main loop: 64 pieces x 4 unrolled substeps -------------
#pragma unroll 1
  for (int p = 0; p < 64; ++p) {
    const bool pre = p < 63;
    if (pre) coeff_load(p + 1);  // prefetch next piece into regs (vmem queue)

#pragma unroll
    for (int sub = 0; sub < 4; ++sub) {
      const float s0 = 0.25f * (float)sub;  // compile-time

      // ---- stage 1: k1 = f(z)*dX(s0); dx carried in dxm ----
      run_f(0);
      kxA *= dxmA; kxB *= dxmB;
      saccA = kxA; saccB = kxB;
      emit(0.125f * kxA + zrA, 0.125f * kxB + zrB, 1);

      // ---- stage 2: k2 at s0+0.125 ----
      run_f(1);
      {
        const float sb = s0 + 0.125f;
        dxbA = c1A + (c2A + c3A * sb) * sb;
        dxbB = c1B + (c2B + c3B * sb) * sb;
        kxA *= dxbA; kxB *= dxbB;
        saccA += 2.f * kxA; saccB += 2.f * kxB;
        emit(0.125f * kxA + zrA, 0.125f * kxB + zrB, 0);
      }

      // ---- stage 3: k3 at same s as k2 (dx reused) ----
      run_f(0);
      kxA *= dxbA; kxB *= dxbB;
      saccA += 2.f * kxA; saccB += 2.f * kxB;
      emit(0.25f * kxA + zrA, 0.25f * kxB + zrB, 1);

      // ---- stage 4: k4 at t+dt; dxm set for NEXT stage 1 too ----
      run_f(1);
      if (sub == 3) {
        if (pre) {
#pragma unroll
          for (int r = 0; r < 4; ++r) {  // next piece, s=0: c1(next)
            dxmA[r] = cf[r][1];
            dxmB[r] = cf[4 + r][1];
          }
        } else {
          dxmA = c1A + c2A + c3A;  // u=255: clip to piece 63 at s=1
          dxmB = c1B + c2B + c3B;
        }
      } else {
        const float sc = s0 + 0.25f;
        dxmA = c1A + (c2A + c3A * sc) * sc;
        dxmB = c1B + (c2B + c3B * sc) * sc;
      }
      {
        saccA += kxA * dxmA; saccB += kxB * dxmB;
        zrA += (0.25f / 6.f) * saccA;
        zrB += (0.25f / 6.f) * saccB;
        emit(zrA, zrB, 0);  // next step's f-input -> buf0
      }
    }
    if (pre) coeff_adopt();
  }

  // ------------- readout: out = zT @ Wr + br -------------
  __syncthreads();  // all exchange reads done; reuse LDS as fp32 zf[16][132]
  {
    float* zf = (float*)lds;
    *(f32x4*)(zf + l15 * 132 + 32 * wv + 4 * q)      = zrA;
    *(f32x4*)(zf + l15 * 132 + 32 * wv + 16 + 4 * q) = zrB;
  }
  __syncthreads();
  if (tid < 160) {
    const int row = tid / 10, o = tid - row * 10;
    const float* zf = (const float*)lds;
    float acc = br[o];
#pragma unroll 4
    for (int ch = 0; ch < 128; ++ch)
      acc = fmaf(zf[row * 132 + ch], Wr[ch * 10 + o], acc);
    out[(size_t)(row0 + row) * 10 + o] = acc;
  }
}

extern "C" void kernel_launch(void* const* d_in, const int* in_sizes, int n_in,
                              void* d_out, int out_size, void* d_ws, size_t ws_size,
                              hipStream_t stream) {
  const float* z0     = (const float*)d_in[0];
  const float* coeffs = (const float*)d_in[1];
  const float* W1 = (const float*)d_in[2]; const float* b1 = (const float*)d_in[3];
  const float* W2 = (const float*)d_in[4]; const float* b2 = (const float*)d_in[5];
  const float* W3 = (const float*)d_in[6]; const float* b3 = (const float*)d_in[7];
  const float* Wr = (const float*)d_in[8]; const float* br = (const float*)d_in[9];
  hipLaunchKernelGGL(cde_fused, dim3(256), dim3(256), 0, stream,
                     z0, coeffs, W1, b1, W2, b2, W3, b3, Wr, br, (float*)d_out);
}

// Round 15
// 710.323 us; speedup vs baseline: 1.0890x; 1.0295x over previous
//
#include <hip/hip_runtime.h>
#include <hip/hip_bf16.h>
#include <math.h>

// NeuralCDE fused kernel, round 15 = round 12 (693us champion) + LDS-only
// hot-loop barrier (no vmcnt drain -> coeff prefetch latency fully hidden).
// 256 blocks x 256 threads (4 waves); block owns 16 batch rows for all 256
// RK4 steps; wave w owns output channels [32w,32w+32). Operand-swapped MFMA
// (W^T = A in regs, X^T = B from LDS) with the diagonal register identity
// (k = 32*slice + 16(i>>2) + 4q + (i&3)): a wave's D-frag after act+cvt_pk IS
// its own-slice B-operand -> own-slice MFMAs + bias-init issue PRE-barrier,
// 3 ds_read_b128 post-barrier, exchange write is one ds_write_b128. Weights
// rotation-ordered (wave w keeps slice (w+j)&3 at index j): all hot-loop
// indices compile-time literals. Single depth-4 MFMA chains (P/Q split is a
// proven regression: r8 +110us, r13 +80us). Scalar epilogue math (f32x4
// epilogue was a proven regression: r14 +38us).
// Barrier: lgkmcnt(0) + s_barrier with sched_barrier(0) on BOTH sides of
// s_barrier (rule #18: ds ops/MFMAs can hoist across the IntrNoMem s_barrier
// intrinsic — r11's race). vmcnt is never drained in-loop; the compiler's
// auto-wait for cf lands before its stage-4 use, ~4 steps after issue.

typedef short bf16x8 __attribute__((ext_vector_type(8)));
typedef float f32x4  __attribute__((ext_vector_type(4)));
typedef unsigned int u32x4 __attribute__((ext_vector_type(4)));

__device__ __forceinline__ f32x4 MFMA16(bf16x8 a, bf16x8 b, f32x4 c) {
  return __builtin_amdgcn_mfma_f32_16x16x32_bf16(a, b, c, 0, 0, 0);
}

__device__ __forceinline__ unsigned short f2bf(float x) {  // weight prep only
  unsigned int u = __float_as_uint(x);
  u += 0x7FFFu + ((u >> 16) & 1u);
  return (unsigned short)(u >> 16);
}

__device__ __forceinline__ unsigned int cvt_pk(float lo, float hi) {
  unsigned int r;  // D[15:0]=bf16(lo), D[31:16]=bf16(hi), RNE
  asm("v_cvt_pk_bf16_f32 %0, %1, %2" : "=v"(r) : "v"(lo), "v"(hi));
  return r;
}

// LDS-only barrier: drains ds ops, leaves global loads in flight. The
// sched_barrier(0) pair pins every instruction on its side of s_barrier
// (rule #18: plain asm "memory" clobbers do NOT order the s_barrier
// intrinsic itself, which is IntrNoMem).
__device__ __forceinline__ void barrier_lds() {
  asm volatile("s_waitcnt lgkmcnt(0)" ::: "memory");
  __builtin_amdgcn_sched_barrier(0);
  __builtin_amdgcn_s_barrier();
  __builtin_amdgcn_sched_barrier(0);
  asm volatile("" ::: "memory");
}

__global__ __launch_bounds__(256, 1) void cde_fused(
    const float* __restrict__ z0, const float* __restrict__ coeffs,
    const float* __restrict__ W1, const float* __restrict__ b1,
    const float* __restrict__ W2, const float* __restrict__ b2,
    const float* __restrict__ W3, const float* __restrict__ b3,
    const float* __restrict__ Wr, const float* __restrict__ br,
    float* __restrict__ out) {
  // [2][16 rows][136 shorts]; row stride 272 B; slice s at byte-offset 64s.
  __shared__ __align__(16) unsigned short zbuf[2][16][136];
  char* const lds = (char*)zbuf;

  const int tid  = (int)threadIdx.x;
  const int lane = tid & 63;
  const int wv   = tid >> 6;        // wave 0..3 (owns k-slice wv)
  const int l15  = lane & 15;       // batch row within tile
  const int q    = lane >> 4;       // 0..3
  const int row0 = (int)blockIdx.x * 16;

  // exchange addresses: slice s lives at byte l15*272 + 64s + 16q
  const int exb  = l15 * 272 + 16 * q;
  const int ownb = exb + 64 * wv;                       // our b128 write
  const int off1 = exb + 64 * ((wv + 1) & 3);           // read, rotation j=1
  const int off2 = exb + 64 * ((wv + 2) & 3);           // j=2
  const int off3 = exb + 64 * ((wv + 3) & 3);           // j=3

  // ------------- weight A-frags, rotation-ordered, B-identity K-dim ---------
  // index [mt][j] holds slice s=(wv+j)&3: elem i = W[32s+16(i>>2)+4q+(i&3)][col]
  bf16x8 wf1[2][4], wf2[2][4], wf3[2][4];
#pragma unroll
  for (int mt = 0; mt < 2; ++mt) {
    const int col = 32 * wv + 16 * mt + l15;
#pragma unroll
    for (int js = 0; js < 4; ++js) {
      const int s = (wv + js) & 3;
      bf16x8 fa, fb, fc;
#pragma unroll
      for (int i = 0; i < 8; ++i) {
        const int k = 32 * s + 16 * (i >> 2) + 4 * q + (i & 3);
        fa[i] = (short)f2bf(W1[k * 128 + col]);
        fb[i] = (short)f2bf(W2[k * 128 + col]);
        fc[i] = (short)f2bf(W3[k * 128 + col]);
      }
      wf1[mt][js] = fa; wf2[mt][js] = fb; wf3[mt][js] = fc;
    }
  }
  // biases (accumulator init): D elem r of tile mt = ch 32wv+16mt+4q+r
  f32x4 bv1[2], bv2[2], bv3[2];
#pragma unroll
  for (int mt = 0; mt < 2; ++mt) {
    bv1[mt] = *(const f32x4*)(b1 + 32 * wv + 16 * mt + 4 * q);
    bv2[mt] = *(const f32x4*)(b2 + 32 * wv + 16 * mt + 4 * q);
    bv3[mt] = *(const f32x4*)(b3 + 32 * wv + 16 * mt + 4 * q);
  }

  // ------------- coeff registers (e = mt*4+r -> row l15, ch 32wv+16mt+4q+r) --
  f32x4 cf[8];
  auto coeff_load = [&](int p) {
    const float* cb = coeffs + ((size_t)(row0 + l15) * 64 + p) * 512;
#pragma unroll
    for (int mt = 0; mt < 2; ++mt)
#pragma unroll
      for (int r = 0; r < 4; ++r)
        cf[mt * 4 + r] = *(const f32x4*)(cb + (32 * wv + 16 * mt + 4 * q + r) * 4);
  };
  float c1v[8], c2b[8], c3b[8];  // c1, 2*c2, 3*c3
  auto coeff_adopt = [&]() {
#pragma unroll
    for (int e = 0; e < 8; ++e) {
      c1v[e] = cf[e][1]; c2b[e] = 2.f * cf[e][2]; c3b[e] = 3.f * cf[e][3];
    }
  };

  // own B-frag registers (packed words, doubles as the LDS exchange payload)
  u32x4 zb;
  auto emit = [&](const float(&h)[8], int wbuf) {  // pack + keep + write b128
    u32x4 t;
    t[0] = cvt_pk(h[0], h[1]); t[1] = cvt_pk(h[2], h[3]);
    t[2] = cvt_pk(h[4], h[5]); t[3] = cvt_pk(h[6], h[7]);
    zb = t;
    *(u32x4*)(lds + wbuf * 4352 + ownb) = t;
  };

  // ------------- prologue -------------
  float zr[8];
  {
    const float* zp = z0 + (size_t)(row0 + l15) * 128 + 32 * wv + 4 * q;
    const f32x4 za = *(const f32x4*)zp;
    const f32x4 zc = *(const f32x4*)(zp + 16);
#pragma unroll
    for (int r = 0; r < 4; ++r) { zr[r] = za[r]; zr[4 + r] = zc[r]; }
  }
  coeff_load(0);
  coeff_adopt();
  {
    float h[8];
#pragma unroll
    for (int e = 0; e < 8; ++e) h[e] = zr[e];
    emit(h, 0);
  }
  __syncthreads();  // prologue: full barrier once

  float kx[8], sacc[8], dxb[8], dxm[8];
#pragma unroll
  for (int e = 0; e < 8; ++e) dxm[e] = c1v[e];  // dX at t=0 (s=0, piece 0)

  // one layer: 2 own-slice MFMAs pre-barrier (from zb regs), then 3 reads +
  // 6 MFMAs; single depth-4 chain per tile; ALL array indices literal.
  auto layer = [&](const bf16x8(&wf)[2][4], const f32x4(&bv)[2], int rb,
                   f32x4& A0, f32x4& A1) {
    const bf16x8 xo = __builtin_bit_cast(bf16x8, zb);
    f32x4 a0 = MFMA16(wf[0][0], xo, bv[0]);
    f32x4 a1 = MFMA16(wf[1][0], xo, bv[1]);
    barrier_lds();
    const char* base = lds + rb * 4352;
    const bf16x8 x1 = *(const bf16x8*)(base + off1);
    const bf16x8 x2 = *(const bf16x8*)(base + off2);
    const bf16x8 x3 = *(const bf16x8*)(base + off3);
    a0 = MFMA16(wf[0][1], x1, a0);
    a1 = MFMA16(wf[1][1], x1, a1);
    a0 = MFMA16(wf[0][2], x2, a0);
    a1 = MFMA16(wf[1][2], x2, a1);
    a0 = MFMA16(wf[0][3], x3, a0);
    a1 = MFMA16(wf[1][3], x3, a1);
    A0 = a0; A1 = a1;
  };

  // one MLP eval; exchange buffers: L1 rd sp wr sp^1, L2 rd sp^1 wr sp,
  // L3 rd sp; result (incl. b3) -> kx
  auto run_f = [&](int sp) {
    f32x4 A0, A1;
    float h[8];
    layer(wf1, bv1, sp, A0, A1);
#pragma unroll
    for (int r = 0; r < 4; ++r) {  // ELU(v) = max(v, exp(min(v,0))-1)
      h[r]     = fmaxf(A0[r], __expf(fminf(A0[r], 0.f)) - 1.f);
      h[4 + r] = fmaxf(A1[r], __expf(fminf(A1[r], 0.f)) - 1.f);
    }
    emit(h, sp ^ 1);
    layer(wf2, bv2, sp ^ 1, A0, A1);
#pragma unroll
    for (int r = 0; r < 4; ++r) {
      h[r] = fmaxf(A0[r], 0.f); h[4 + r] = fmaxf(A1[r], 0.f);  // ReLU
    }
    emit(h, sp);
    layer(wf3, bv3, sp, A0, A1);
#pragma unroll
    for (int r = 0; r < 4; ++r) { kx[r] = A0[r]; kx[4 + r] = A1[r]; }
  };

  // ------------- main loop: 64 pieces x 4 unrolled substeps -------------
#pragma unroll 1
  for (int p = 0; p < 64; ++p) {
    const bool pre = p < 63;
    if (pre) coeff_load(p + 1);  // prefetch; no in-loop barrier drains vmcnt

#pragma unroll
    for (int sub = 0; sub < 4; ++sub) {
      const float s0 = 0.25f * (float)sub;  // compile-time

      // ---- stage 1: k1 = f(z)*dX(s0); dx carried in dxm ----
      run_f(0);
      {
        float h[8];
#pragma unroll
        for (int e = 0; e < 8; ++e) {
          kx[e] *= dxm[e]; sacc[e] = kx[e];
          h[e] = fmaf(0.125f, kx[e], zr[e]);
        }
        emit(h, 1);
      }

      // ---- stage 2: k2 at s0+0.125 ----
      run_f(1);
      {
        const float sb = s0 + 0.125f;
        float h[8];
#pragma unroll
        for (int e = 0; e < 8; ++e) {
          dxb[e] = c1v[e] + (c2b[e] + c3b[e] * sb) * sb;
          kx[e] *= dxb[e]; sacc[e] += 2.f * kx[e];
          h[e] = fmaf(0.125f, kx[e], zr[e]);
        }
        emit(h, 0);
      }

      // ---- stage 3: k3 at same s as k2 (dx reused) ----
      run_f(0);
      {
        float h[8];
#pragma unroll
        for (int e = 0; e < 8; ++e) {
          kx[e] *= dxb[e]; sacc[e] += 2.f * kx[e];
          h[e] = fmaf(0.25f, kx[e], zr[e]);
        }
        emit(h, 1);
      }

      // ---- stage 4: k4 at t+dt; dxm set for NEXT stage 1 too ----
      run_f(1);
      if (sub == 3) {
        if (pre) {
#pragma unroll
          for (int e = 0; e < 8; ++e) dxm[e] = cf[e][1];  // next piece, s=0
        } else {
#pragma unroll
          for (int e = 0; e < 8; ++e) dxm[e] = c1v[e] + c2b[e] + c3b[e];  // s=1
        }
      } else {
        const float sc = s0 + 0.25f;
#pragma unroll
        for (int e = 0; e < 8; ++e)
          dxm[e] = c1v[e] + (c2b[e] + c3b[e] * sc) * sc;
      }
      {
        float h[8];
#pragma unroll
        for (int e = 0; e < 8; ++e) {
          const float k4 = kx[e] * dxm[e];
          sacc[e] += k4;
          zr[e] = fmaf(0.25f / 6.f, sacc[e], zr[e]);
          h[e] = zr[e];
        }
        emit(h, 0);  // next step's f-input -> buf0
      }
    }
    if (pre) coeff_adopt();
  }

  // ------------- readout: out = zT @ Wr + br -------------
  __syncthreads();  // all exchange reads done; reuse LDS as fp32 zf[16][132]
  {
    float* zf = (float*)lds;
    *(f32x4*)(zf + l15 * 132 + 32 * wv + 4 * q)      = f32x4{zr[0], zr[1], zr[2], zr[3]};
    *(f32x4*)(zf + l15 * 132 + 32 * wv + 16 + 4 * q) = f32x4{zr[4], zr[5], zr[6], zr[7]};
  }
  __syncthreads();
  if (tid < 160) {
    const int row = tid / 10, o = tid - row * 10;
    const float* zf = (const float*)lds;
    float acc = br[o];
#pragma unroll 4
    for (int ch = 0; ch < 128; ++ch)
      acc = fmaf(zf[row * 132 + ch], Wr[ch * 10 + o], acc);
    out[(size_t)(row0 + row) * 10 + o] = acc;
  }
}

extern "C" void kernel_launch(void* const* d_in, const int* in_sizes, int n_in,
                              void* d_out, int out_size, void* d_ws, size_t ws_size,
                              hipStream_t stream) {
  const float* z0     = (const float*)d_in[0];
  const float* coeffs = (const float*)d_in[1];
  const float* W1 = (const float*)d_in[2]; const float* b1 = (const float*)d_in[3];
  const float* W2 = (const float*)d_in[4]; const float* b2 = (const float*)d_in[5];
  const float* W3 = (const float*)d_in[6]; const float* b3 = (const float*)d_in[7];
  const float* Wr = (const float*)d_in[8]; const float* br = (const float*)d_in[9];
  hipLaunchKernelGGL(cde_fused, dim3(256), dim3(256), 0, stream,
                     z0, coeffs, W1, b1, W2, b2, W3, b3, Wr, br, (float*)d_out);
}

// Round 16
// 693.132 us; speedup vs baseline: 1.1160x; 1.0248x over previous
//
#include <hip/hip_runtime.h>
#include <hip/hip_bf16.h>
#include <math.h>

// NeuralCDE fused kernel, FINAL = round 12 (693us champion, soak-proven).
// 256 blocks x 256 threads (4 waves); block owns 16 batch rows for all 256
// RK4 steps; wave w owns output channels [32w,32w+32). Operand-swapped MFMA
// (W^T = A in regs, X^T = B from LDS) with the diagonal register identity
// (k = 32*slice + 16(i>>2) + 4q + (i&3)): a wave's D-frag after act+cvt_pk IS
// its own-slice B-operand -> own-slice MFMAs + bias-init issue PRE-barrier,
// 3 ds_read_b128 post-barrier, exchange write is one ds_write_b128. Weights
// rotation-ordered (wave w keeps slice (w+j)&3 at index j): all hot-loop
// indices compile-time literals. Single depth-4 MFMA chains. All sync is
// real __syncthreads().
// Negative results (kept for the record): P/Q chain split (r8 +110us, r13
// +80us), f32x4 epilogue (r14 +38us), asm lgkm barrier (r11 RACE, r15 +17us),
// 8-wave N=16 (+190us), 8-row 2-block/CU (+330us), per-wave full-MLP (+1.8ms).

typedef short bf16x8 __attribute__((ext_vector_type(8)));
typedef float f32x4  __attribute__((ext_vector_type(4)));
typedef unsigned int u32x4 __attribute__((ext_vector_type(4)));

__device__ __forceinline__ f32x4 MFMA16(bf16x8 a, bf16x8 b, f32x4 c) {
  return __builtin_amdgcn_mfma_f32_16x16x32_bf16(a, b, c, 0, 0, 0);
}

__device__ __forceinline__ unsigned short f2bf(float x) {  // weight prep only
  unsigned int u = __float_as_uint(x);
  u += 0x7FFFu + ((u >> 16) & 1u);
  return (unsigned short)(u >> 16);
}

__device__ __forceinline__ unsigned int cvt_pk(float lo, float hi) {
  unsigned int r;  // D[15:0]=bf16(lo), D[31:16]=bf16(hi), RNE
  asm("v_cvt_pk_bf16_f32 %0, %1, %2" : "=v"(r) : "v"(lo), "v"(hi));
  return r;
}

__global__ __launch_bounds__(256, 1) void cde_fused(
    const float* __restrict__ z0, const float* __restrict__ coeffs,
    const float* __restrict__ W1, const float* __restrict__ b1,
    const float* __restrict__ W2, const float* __restrict__ b2,
    const float* __restrict__ W3, const float* __restrict__ b3,
    const float* __restrict__ Wr, const float* __restrict__ br,
    float* __restrict__ out) {
  // [2][16 rows][136 shorts]; row stride 272 B; slice s at byte-offset 64s.
  __shared__ __align__(16) unsigned short zbuf[2][16][136];
  char* const lds = (char*)zbuf;

  const int tid  = (int)threadIdx.x;
  const int lane = tid & 63;
  const int wv   = tid >> 6;        // wave 0..3 (owns k-slice wv)
  const int l15  = lane & 15;       // batch row within tile
  const int q    = lane >> 4;       // 0..3
  const int row0 = (int)blockIdx.x * 16;

  // exchange addresses: slice s lives at byte l15*272 + 64s + 16q
  const int exb  = l15 * 272 + 16 * q;
  const int ownb = exb + 64 * wv;                       // our b128 write
  const int off1 = exb + 64 * ((wv + 1) & 3);           // read, rotation j=1
  const int off2 = exb + 64 * ((wv + 2) & 3);           // j=2
  const int off3 = exb + 64 * ((wv + 3) & 3);           // j=3

  // ------------- weight A-frags, rotation-ordered, B-identity K-dim ---------
  // index [mt][j] holds slice s=(wv+j)&3: elem i = W[32s+16(i>>2)+4q+(i&3)][col]
  bf16x8 wf1[2][4], wf2[2][4], wf3[2][4];
#pragma unroll
  for (int mt = 0; mt < 2; ++mt) {
    const int col = 32 * wv + 16 * mt + l15;
#pragma unroll
    for (int js = 0; js < 4; ++js) {
      const int s = (wv + js) & 3;
      bf16x8 fa, fb, fc;
#pragma unroll
      for (int i = 0; i < 8; ++i) {
        const int k = 32 * s + 16 * (i >> 2) + 4 * q + (i & 3);
        fa[i] = (short)f2bf(W1[k * 128 + col]);
        fb[i] = (short)f2bf(W2[k * 128 + col]);
        fc[i] = (short)f2bf(W3[k * 128 + col]);
      }
      wf1[mt][js] = fa; wf2[mt][js] = fb; wf3[mt][js] = fc;
    }
  }
  // biases (accumulator init): D elem r of tile mt = ch 32wv+16mt+4q+r
  f32x4 bv1[2], bv2[2], bv3[2];
#pragma unroll
  for (int mt = 0; mt < 2; ++mt) {
    bv1[mt] = *(const f32x4*)(b1 + 32 * wv + 16 * mt + 4 * q);
    bv2[mt] = *(const f32x4*)(b2 + 32 * wv + 16 * mt + 4 * q);
    bv3[mt] = *(const f32x4*)(b3 + 32 * wv + 16 * mt + 4 * q);
  }

  // ------------- coeff registers (e = mt*4+r -> row l15, ch 32wv+16mt+4q+r) --
  f32x4 cf[8];
  auto coeff_load = [&](int p) {
    const float* cb = coeffs + ((size_t)(row0 + l15) * 64 + p) * 512;
#pragma unroll
    for (int mt = 0; mt < 2; ++mt)
#pragma unroll
      for (int r = 0; r < 4; ++r)
        cf[mt * 4 + r] = *(const f32x4*)(cb + (32 * wv + 16 * mt + 4 * q + r) * 4);
  };
  float c1v[8], c2b[8], c3b[8];  // c1, 2*c2, 3*c3
  auto coeff_adopt = [&]() {
#pragma unroll
    for (int e = 0; e < 8; ++e) {
      c1v[e] = cf[e][1]; c2b[e] = 2.f * cf[e][2]; c3b[e] = 3.f * cf[e][3];
    }
  };

  // own B-frag registers (packed words, doubles as the LDS exchange payload)
  u32x4 zb;
  auto emit = [&](const float(&h)[8], int wbuf) {  // pack + keep + write b128
    u32x4 t;
    t[0] = cvt_pk(h[0], h[1]); t[1] = cvt_pk(h[2], h[3]);
    t[2] = cvt_pk(h[4], h[5]); t[3] = cvt_pk(h[6], h[7]);
    zb = t;
    *(u32x4*)(lds + wbuf * 4352 + ownb) = t;
  };

  // ------------- prologue -------------
  float zr[8];
  {
    const float* zp = z0 + (size_t)(row0 + l15) * 128 + 32 * wv + 4 * q;
    const f32x4 za = *(const f32x4*)zp;
    const f32x4 zc = *(const f32x4*)(zp + 16);
#pragma unroll
    for (int r = 0; r < 4; ++r) { zr[r] = za[r]; zr[4 + r] = zc[r]; }
  }
  coeff_load(0);
  coeff_adopt();
  {
    float h[8];
#pragma unroll
    for (int e = 0; e < 8; ++e) h[e] = zr[e];
    emit(h, 0);
  }

  float kx[8], sacc[8], dxb[8], dxm[8];
#pragma unroll
  for (int e = 0; e < 8; ++e) dxm[e] = c1v[e];  // dX at t=0 (s=0, piece 0)

  // one layer: 2 own-slice MFMAs pre-barrier (from zb regs), then 3 reads +
  // 6 MFMAs; single depth-4 chain per tile; ALL array indices literal.
  auto layer = [&](const bf16x8(&wf)[2][4], const f32x4(&bv)[2], int rb,
                   f32x4& A0, f32x4& A1) {
    const bf16x8 xo = __builtin_bit_cast(bf16x8, zb);
    f32x4 a0 = MFMA16(wf[0][0], xo, bv[0]);
    f32x4 a1 = MFMA16(wf[1][0], xo, bv[1]);
    __syncthreads();
    const char* base = lds + rb * 4352;
    const bf16x8 x1 = *(const bf16x8*)(base + off1);
    const bf16x8 x2 = *(const bf16x8*)(base + off2);
    const bf16x8 x3 = *(const bf16x8*)(base + off3);
    a0 = MFMA16(wf[0][1], x1, a0);
    a1 = MFMA16(wf[1][1], x1, a1);
    a0 = MFMA16(wf[0][2], x2, a0);
    a1 = MFMA16(wf[1][2], x2, a1);
    a0 = MFMA16(wf[0][3], x3, a0);
    a1 = MFMA16(wf[1][3], x3, a1);
    A0 = a0; A1 = a1;
  };

  // one MLP eval; exchange buffers: L1 rd sp wr sp^1, L2 rd sp^1 wr sp,
  // L3 rd sp; result (incl. b3) -> kx
  auto run_f = [&](int sp) {
    f32x4 A0, A1;
    float h[8];
    layer(wf1, bv1, sp, A0, A1);
#pragma unroll
    for (int r = 0; r < 4; ++r) {  // ELU(v) = max(v, exp(min(v,0))-1)
      h[r]     = fmaxf(A0[r], __expf(fminf(A0[r], 0.f)) - 1.f);
      h[4 + r] = fmaxf(A1[r], __expf(fminf(A1[r], 0.f)) - 1.f);
    }
    emit(h, sp ^ 1);
    layer(wf2, bv2, sp ^ 1, A0, A1);
#pragma unroll
    for (int r = 0; r < 4; ++r) {
      h[r] = fmaxf(A0[r], 0.f); h[4 + r] = fmaxf(A1[r], 0.f);  // ReLU
    }
    emit(h, sp);
    layer(wf3, bv3, sp, A0, A1);
#pragma unroll
    for (int r = 0; r < 4; ++r) { kx[r] = A0[r]; kx[4 + r] = A1[r]; }
  };

  // ------------- main loop: 64 pieces x 4 unrolled substeps -------------
#pragma unroll 1
  for (int p = 0; p < 64; ++p) {
    const bool pre = p < 63;
    if (pre) coeff_load(p + 1);  // prefetch next piece into regs (vmem queue)

#pragma unroll
    for (int sub = 0; sub < 4; ++sub) {
      const float s0 = 0.25f * (float)sub;  // compile-time

      // ---- stage 1: k1 = f(z)*dX(s0); dx carried in dxm ----
      run_f(0);
      {
        float h[8];
#pragma unroll
        for (int e = 0; e < 8; ++e) {
          kx[e] *= dxm[e]; sacc[e] = kx[e];
          h[e] = fmaf(0.125f, kx[e], zr[e]);
        }
        emit(h, 1);
      }

      // ---- stage 2: k2 at s0+0.125 ----
      run_f(1);
      {
        const float sb = s0 + 0.125f;
        float h[8];
#pragma unroll
        for (int e = 0; e < 8; ++e) {
          dxb[e] = c1v[e] + (c2b[e] + c3b[e] * sb) * sb;
          kx[e] *= dxb[e]; sacc[e] += 2.f * kx[e];
          h[e] = fmaf(0.125f, kx[e], zr[e]);
        }
        emit(h, 0);
      }

      // ---- stage 3: k3 at same s as k2 (dx reused) ----
      run_f(0);
      {
        float h[8];
#pragma unroll
        for (int e = 0; e < 8; ++e) {
          kx[e] *= dxb[e]; sacc[e] += 2.f * kx[e];
          h[e] = fmaf(0.25f, kx[e], zr[e]);
        }
        emit(h, 1);
      }

      // ---- stage 4: k4 at t+dt; dxm set for NEXT stage 1 too ----
      run_f(1);
      if (sub == 3) {
        if (pre) {
#pragma unroll
          for (int e = 0; e < 8; ++e) dxm[e] = cf[e][1];  // next piece, s=0
        } else {
#pragma unroll
          for (int e = 0; e < 8; ++e) dxm[e] = c1v[e] + c2b[e] + c3b[e];  // s=1
        }
      } else {
        const float sc = s0 + 0.25f;
#pragma unroll
        for (int e = 0; e < 8; ++e)
          dxm[e] = c1v[e] + (c2b[e] + c3b[e] * sc) * sc;
      }
      {
        float h[8];
#pragma unroll
        for (int e = 0; e < 8; ++e) {
          const float k4 = kx[e] * dxm[e];
          sacc[e] += k4;
          zr[e] = fmaf(0.25f / 6.f, sacc[e], zr[e]);
          h[e] = zr[e];
        }
        emit(h, 0);  // next step's f-input -> buf0
      }
    }
    if (pre) coeff_adopt();
  }

  // ------------- readout: out = zT @ Wr + br -------------
  __syncthreads();  // all exchange reads done; reuse LDS as fp32 zf[16][132]
  {
    float* zf = (float*)lds;
    *(f32x4*)(zf + l15 * 132 + 32 * wv + 4 * q)      = f32x4{zr[0], zr[1], zr[2], zr[3]};
    *(f32x4*)(zf + l15 * 132 + 32 * wv + 16 + 4 * q) = f32x4{zr[4], zr[5], zr[6], zr[7]};
  }
  __syncthreads();
  if (tid < 160) {
    const int row = tid / 10, o = tid - row * 10;
    const float* zf = (const float*)lds;
    float acc = br[o];
#pragma unroll 4
    for (int ch = 0; ch < 128; ++ch)
      acc = fmaf(zf[row * 132 + ch], Wr[ch * 10 + o], acc);
    out[(size_t)(row0 + row) * 10 + o] = acc;
  }
}

extern "C" void kernel_launch(void* const* d_in, const int* in_sizes, int n_in,
                              void* d_out, int out_size, void* d_ws, size_t ws_size,
                              hipStream_t stream) {
  const float* z0     = (const float*)d_in[0];
  const float* coeffs = (const float*)d_in[1];
  const float* W1 = (const float*)d_in[2]; const float* b1 = (const float*)d_in[3];
  const float* W2 = (const float*)d_in[4]; const float* b2 = (const float*)d_in[5];
  const float* W3 = (const float*)d_in[6]; const float* b3 = (const float*)d_in[7];
  const float* Wr = (const float*)d_in[8]; const float* br = (const float*)d_in[9];
  hipLaunchKernelGGL(cde_fused, dim3(256), dim3(256), 0, stream,
                     z0, coeffs, W1, b1, W2, b2, W3, b3, Wr, br, (float*)d_out);
}